// Round 4
// baseline (1236.126 us; speedup 1.0000x reference)
//
#include <hip/hip_runtime.h>
#include <stdint.h>

// ---------------------------------------------------------------------------
// MHA fwd: B=2,S=2048,D=1024,H=16,DK=DV=64. fp32 I/O, bf16 MFMA, fp32 accum.
// out = softmax(mask(QK^T/8)) @ V @ Wo + bo ; also returns attention matrix.
//
// ROUND-4 DIAGNOSTIC: attn_kern launched 3x (idempotent). Known totals:
// overhead ~497us, pipeline ~340us (round-3 2x-pipeline probe).
// attn cost = (dur - 837)/2.
// ---------------------------------------------------------------------------

typedef __attribute__((ext_vector_type(8))) __bf16 bf16x8;
typedef __attribute__((ext_vector_type(8))) short short8;
typedef __attribute__((ext_vector_type(4))) float f32x4;

static __device__ __forceinline__ f32x4 mfma_bf16(short8 a, short8 b, f32x4 c) {
  return __builtin_amdgcn_mfma_f32_16x16x32_bf16(
      __builtin_bit_cast(bf16x8, a), __builtin_bit_cast(bf16x8, b), c, 0, 0, 0);
}

static __device__ __forceinline__ unsigned short f2bf(float f) {
  unsigned int u = __float_as_uint(f);
  u += 0x7fffu + ((u >> 16) & 1u);           // round-to-nearest-even
  return (unsigned short)(u >> 16);
}

// global->LDS direct copy, 16B per lane. LDS dest is wave-uniform base + lane*16.
static __device__ __forceinline__ void gload_lds16(const void* g, void* l) {
  __builtin_amdgcn_global_load_lds(
      (__attribute__((address_space(1))) void*)(uintptr_t)(g),
      (__attribute__((address_space(3))) void*)(uintptr_t)(l), 16, 0, 0);
}

// ---------------------------------------------------------------------------
// fp32 -> bf16 conversion for query/key/value activations. 8 floats/thread.
// ---------------------------------------------------------------------------
__global__ __launch_bounds__(256) void conv_f32_bf16(
    const float* q, const float* k, const float* v,
    unsigned short* oq, unsigned short* ok, unsigned short* ov) {
  const float* src = (blockIdx.z == 0) ? q : (blockIdx.z == 1) ? k : v;
  unsigned short* dst = (blockIdx.z == 0) ? oq : (blockIdx.z == 1) ? ok : ov;
  const int i = (blockIdx.x * 256 + threadIdx.x) * 8;
  const float4 a = *(const float4*)&src[i];
  const float4 b = *(const float4*)&src[i + 4];
  unsigned short r[8] = {f2bf(a.x), f2bf(a.y), f2bf(a.z), f2bf(a.w),
                         f2bf(b.x), f2bf(b.y), f2bf(b.z), f2bf(b.w)};
  *(uint4*)&dst[i] = *(uint4*)r;
}

// ---------------------------------------------------------------------------
// Weight transpose+convert: WT[n][k] = bf16(W[k][n]), 1024x1024, z = matrix.
// ---------------------------------------------------------------------------
__global__ __launch_bounds__(256) void transpose_w(
    const float* w0, const float* w1, const float* w2, const float* w3,
    unsigned short* o0, unsigned short* o1,
    unsigned short* o2, unsigned short* o3) {
  const float* src = (blockIdx.z == 0) ? w0 : (blockIdx.z == 1) ? w1
                                         : (blockIdx.z == 2) ? w2 : w3;
  unsigned short* dst = (blockIdx.z == 0) ? o0 : (blockIdx.z == 1) ? o1
                                           : (blockIdx.z == 2) ? o2 : o3;
  __shared__ unsigned short tile[64 * 66];
  const int t = threadIdx.x;
  const int r0 = blockIdx.y * 64, c0 = blockIdx.x * 64;
#pragma unroll
  for (int i = 0; i < 4; ++i) {
    const int slot = i * 256 + t;
    const int row = slot >> 4, cg = slot & 15;
    const float4 v = *(const float4*)&src[(r0 + row) * 1024 + c0 + cg * 4];
    unsigned int p0 = (unsigned int)f2bf(v.x) | ((unsigned int)f2bf(v.y) << 16);
    unsigned int p1 = (unsigned int)f2bf(v.z) | ((unsigned int)f2bf(v.w) << 16);
    unsigned int* dp = (unsigned int*)&tile[row * 66 + cg * 4];
    dp[0] = p0;
    dp[1] = p1;
  }
  __syncthreads();
#pragma unroll
  for (int i = 0; i < 2; ++i) {
    const int slot = i * 256 + t;
    const int orow = slot >> 3, kg = slot & 7;
    unsigned short vals[8];
#pragma unroll
    for (int j = 0; j < 8; ++j) vals[j] = tile[(kg * 8 + j) * 66 + orow];
    *(uint4*)&dst[(c0 + orow) * 1024 + r0 + kg * 8] = *(uint4*)vals;
  }
}

// ---------------------------------------------------------------------------
// Pack mask into bitmask: bits[w] bit L = (mask[w*64+L] != 0).  131072 words.
// ---------------------------------------------------------------------------
__global__ __launch_bounds__(256) void mask_prep(const int* __restrict__ mask,
                                                 unsigned long long* __restrict__ bits) {
  const int wid = (blockIdx.x * 256 + threadIdx.x) >> 6;  // 2048 waves
  const int lane = threadIdx.x & 63;
  for (int w = wid; w < 131072; w += 2048) {
    const int m = mask[w * 64 + lane];
    const unsigned long long b = __ballot(m != 0);
    if (lane == 0) bits[w] = b;
  }
}

// ---------------------------------------------------------------------------
// GEMM: C[4096,1024] = A[4096,1024](bf16) @ BT[1024,1024]^T(bf16) + bias(f32).
// mode 0: bf16 row-major store. mode 1: bf16 V head-transpose Vt[b][col][s].
// mode 2: fp32 row-major store (final output).
// 128x128 tile, 4 waves each 64x64, BK=64, global_load_lds staging.
// ---------------------------------------------------------------------------
struct GArg {
  const unsigned short* A;
  const unsigned short* BT;
  const float* bias;
  void* C;
  int mode;
};

__global__ __launch_bounds__(256) void gemm_bt(GArg ga, GArg gb, GArg gc) {
  const GArg g = (blockIdx.z == 0) ? ga : (blockIdx.z == 1) ? gb : gc;
  __shared__ alignas(16) unsigned short ash[128 * 64];
  __shared__ alignas(16) unsigned short bsh[128 * 64];
  const int t = threadIdx.x;
  const int wave = t >> 6, lane = t & 63;
  const int m0 = blockIdx.y * 128, n0 = blockIdx.x * 128;
  const int wm = (wave >> 1) * 64, wn = (wave & 1) * 64;
  const int c = lane & 15, gq = lane >> 4;
  const int srow = wave * 8 + (lane >> 3);
  const int scol = (lane & 7) * 8;

  f32x4 zero = {0.f, 0.f, 0.f, 0.f};
  f32x4 acc[4][4];
#pragma unroll
  for (int i = 0; i < 4; ++i)
#pragma unroll
    for (int j = 0; j < 4; ++j) acc[i][j] = zero;

  for (int kk = 0; kk < 16; ++kk) {
    __syncthreads();
    const int kbase = kk * 64;
#pragma unroll
    for (int i = 0; i < 4; ++i) {
      gload_lds16(&g.A[(m0 + i * 32 + srow) * 1024 + kbase + scol],
                  &ash[(i * 32 + wave * 8) * 64]);
      gload_lds16(&g.BT[(n0 + i * 32 + srow) * 1024 + kbase + scol],
                  &bsh[(i * 32 + wave * 8) * 64]);
    }
    __syncthreads();
#pragma unroll
    for (int ks = 0; ks < 2; ++ks) {
      short8 af[4], bf[4];
#pragma unroll
      for (int mt = 0; mt < 4; ++mt)
        af[mt] = *(const short8*)&ash[(wm + mt * 16 + c) * 64 + ks * 32 + gq * 8];
#pragma unroll
      for (int nt = 0; nt < 4; ++nt)
        bf[nt] = *(const short8*)&bsh[(wn + nt * 16 + c) * 64 + ks * 32 + gq * 8];
#pragma unroll
      for (int mt = 0; mt < 4; ++mt)
#pragma unroll
        for (int nt = 0; nt < 4; ++nt)
          acc[mt][nt] = mfma_bf16(af[mt], bf[nt], acc[mt][nt]);
    }
  }
#pragma unroll
  for (int nt = 0; nt < 4; ++nt) {
    const int gcol = n0 + wn + nt * 16 + c;
    const float bia = g.bias[gcol];
#pragma unroll
    for (int mt = 0; mt < 4; ++mt) {
#pragma unroll
      for (int r = 0; r < 4; ++r) {
        const int grow = m0 + wm + mt * 16 + gq * 4 + r;
        const float v = acc[mt][nt][r] + bia;
        if (g.mode == 0) {
          ((unsigned short*)g.C)[grow * 1024 + gcol] = f2bf(v);
        } else if (g.mode == 1) {  // Vt[b][gcol][s]
          ((unsigned short*)g.C)[((grow >> 11) << 21) + (gcol << 11) + (grow & 2047)] =
              f2bf(v);
        } else {  // fp32 row-major (final out)
          ((float*)g.C)[grow * 1024 + gcol] = v;
        }
      }
    }
  }
}

// ---------------------------------------------------------------------------
// Attention: per block = (qtile 64 rows, head, batch). 4 waves x 16 q-rows.
// Round-2 structure; phase-2 steady-state wait restored to the exact
// vmcnt(8): queue is [L_kv(4), S_{kv-1}(4), L_{kv+1}(4)]; in-order
// retirement means draining to 8 retires exactly L_kv without forcing the
// att stores S_{kv-1} to complete (which vmcnt(4) did, serializing ~100-200
// cy/iter of store retirement).
// ---------------------------------------------------------------------------
__global__ __launch_bounds__(256) void attn_kern(
    const unsigned short* __restrict__ Qb, const unsigned short* __restrict__ Kb,
    const unsigned short* __restrict__ Vt, const unsigned long long* __restrict__ mbits,
    float* __restrict__ att, unsigned short* __restrict__ Obuf) {
  const int id0 = blockIdx.x + 32 * (blockIdx.y + 16 * blockIdx.z);
  const int id = (id0 & 7) * 128 + (id0 >> 3);
  const int qt = id & 31, h = (id >> 5) & 15, b = id >> 9;
  const int t = threadIdx.x, wave = t >> 6, lane = t & 63;
  const int q0 = qt * 64;
  const int c = lane & 15, gq = lane >> 4;
  const int srow = lane >> 3;                       // 0..7
  const int scol_sw = ((lane & 7) ^ srow) * 8;      // pre-swizzled source col
  const float SCALE = 0.125f * 1.44269504088896341f;  // (1/8)*log2(e)

  __shared__ alignas(16) unsigned short kt[2][64 * 64];  // 16 KB
  __shared__ alignas(16) unsigned short vt[2][64 * 64];  // 16 KB
  __shared__ alignas(16) float psf[4 * 16 * 64];         // 16 KB (per-wave 1024f)

  auto stage_k = [&](int kvt, int bu) {
#pragma unroll
    for (int i = 0; i < 2; ++i)
      gload_lds16(&Kb[(b * 2048 + kvt * 64 + wave * 16 + i * 8 + srow) * 1024 +
                      h * 64 + scol_sw],
                  &kt[bu][(wave * 16 + i * 8) * 64]);
  };
  auto stage_v = [&](int kvt, int bu) {
#pragma unroll
    for (int i = 0; i < 2; ++i)
      gload_lds16(&Vt[(b << 21) + (h * 64 + wave * 16 + i * 8 + srow) * 2048 +
                      kvt * 64 + scol_sw],
                  &vt[bu][(wave * 16 + i * 8) * 64]);
  };
  auto rdcol = [&](int ks) { return (((ks * 4 + gq) ^ (c & 7)) * 8); };

  stage_k(0, 0);

  unsigned long long* msk = (unsigned long long*)psf;  // [64][32]
  {
    const int row = t >> 2, c8 = (t & 3) * 8;
    const unsigned long long* src = &mbits[(unsigned)(b * 2048 + q0 + row) * 32 + c8];
#pragma unroll
    for (int j = 0; j < 8; ++j) msk[row * 32 + c8 + j] = src[j];
  }
  unsigned long long mlo[4], mhi[4];
#pragma unroll
  for (int r = 0; r < 4; ++r) {
    const int row = wave * 16 + gq * 4 + r;
    unsigned long long lo = 0, hi = 0;
#pragma unroll
    for (int kvi = 0; kvi < 16; ++kvi) {
      const unsigned long long w0 = msk[row * 32 + kvi] >> c;
      const unsigned long long w1 = msk[row * 32 + 16 + kvi] >> c;
      const unsigned long long n0 =
          (w0 & 1) | ((w0 >> 15) & 2) | ((w0 >> 30) & 4) | ((w0 >> 45) & 8);
      const unsigned long long n1 =
          (w1 & 1) | ((w1 >> 15) & 2) | ((w1 >> 30) & 4) | ((w1 >> 45) & 8);
      lo |= n0 << (kvi * 4);
      hi |= n1 << (kvi * 4);
    }
    mlo[r] = lo;
    mhi[r] = hi;
  }

  short8 aq[2];
  {
    const unsigned short* qrow = &Qb[(b * 2048 + q0 + wave * 16 + c) * 1024 + h * 64];
    aq[0] = *(const short8*)&qrow[gq * 8];
    aq[1] = *(const short8*)&qrow[32 + gq * 8];
  }

  asm volatile("s_waitcnt vmcnt(0) lgkmcnt(0)" ::: "memory");
  __builtin_amdgcn_s_barrier();
  __builtin_amdgcn_sched_barrier(0);

  const f32x4 zero = {0.f, 0.f, 0.f, 0.f};
  float lsum[4] = {0.f, 0.f, 0.f, 0.f};
  int buf = 0;

#pragma unroll 1
  for (int kv = 0; kv < 32; ++kv) {
    if (kv < 31) {
      stage_k(kv + 1, buf ^ 1);
      asm volatile("s_waitcnt vmcnt(2)" ::: "memory");
    } else {
      asm volatile("s_waitcnt vmcnt(0)" ::: "memory");
    }
    __builtin_amdgcn_s_barrier();
    __builtin_amdgcn_sched_barrier(0);

    f32x4 s[4];
#pragma unroll
    for (int nt = 0; nt < 4; ++nt) s[nt] = zero;
    __builtin_amdgcn_s_setprio(1);
#pragma unroll
    for (int ks = 0; ks < 2; ++ks)
#pragma unroll
      for (int nt = 0; nt < 4; ++nt) {
        const short8 bk = *(const short8*)&kt[buf][(nt * 16 + c) * 64 + rdcol(ks)];
        s[nt] = mfma_bf16(aq[ks], bk, s[nt]);
      }
    __builtin_amdgcn_s_setprio(0);
#pragma unroll
    for (int r = 0; r < 4; ++r) {
      const unsigned long long mr = (kv < 16) ? mlo[r] : mhi[r];
      const unsigned nib = (unsigned)(mr >> ((kv & 15) * 4)) & 0xFu;
#pragma unroll
      for (int nt = 0; nt < 4; ++nt) {
        const float e = ((nib >> nt) & 1u) ? s[nt][r] * SCALE : -30.f;
        lsum[r] += __builtin_amdgcn_exp2f(e);
      }
    }
    asm volatile("s_waitcnt lgkmcnt(0)" ::: "memory");
    __builtin_amdgcn_s_barrier();
    __builtin_amdgcn_sched_barrier(0);
    buf ^= 1;
  }

  float linv[4];
#pragma unroll
  for (int r = 0; r < 4; ++r) {
    float v = lsum[r];
    v += __shfl_xor(v, 1);
    v += __shfl_xor(v, 2);
    v += __shfl_xor(v, 4);
    v += __shfl_xor(v, 8);
    linv[r] = 1.0f / v;
  }

  f32x4 o[4];
#pragma unroll
  for (int nt = 0; nt < 4; ++nt) o[nt] = zero;

  stage_k(0, buf);
  stage_v(0, buf);
  asm volatile("s_waitcnt vmcnt(0)" ::: "memory");
  __builtin_amdgcn_s_barrier();
  __builtin_amdgcn_sched_barrier(0);

#pragma unroll 1
  for (int kv = 0; kv < 32; ++kv) {
    if (kv < 31) {
      stage_k(kv + 1, buf ^ 1);
      stage_v(kv + 1, buf ^ 1);
      // queue worst case: [L_kv(4), S_{kv-1}(4), L_{kv+1}(4)] = 12.
      // vmcnt(8) retires exactly L_kv (oldest 4); att stores keep draining
      // in the background.
      asm volatile("s_waitcnt vmcnt(8)" ::: "memory");
    } else {
      // queue: [L_31(4), S_30(4)] -> vmcnt(4) retires L_31.
      asm volatile("s_waitcnt vmcnt(4)" ::: "memory");
    }
    __builtin_amdgcn_s_barrier();
    __builtin_amdgcn_sched_barrier(0);

    f32x4 s[4];
#pragma unroll
    for (int nt = 0; nt < 4; ++nt) s[nt] = zero;
    __builtin_amdgcn_s_setprio(1);
#pragma unroll
    for (int ks = 0; ks < 2; ++ks)
#pragma unroll
      for (int nt = 0; nt < 4; ++nt) {
        const short8 bk = *(const short8*)&kt[buf][(nt * 16 + c) * 64 + rdcol(ks)];
        s[nt] = mfma_bf16(aq[ks], bk, s[nt]);
      }
    __builtin_amdgcn_s_setprio(0);
#pragma unroll
    for (int r = 0; r < 4; ++r) {
      const unsigned long long mr = (kv < 16) ? mlo[r] : mhi[r];
      const unsigned nib = (unsigned)(mr >> ((kv & 15) * 4)) & 0xFu;
#pragma unroll
      for (int nt = 0; nt < 4; ++nt) {
        const float e = ((nib >> nt) & 1u) ? s[nt][r] * SCALE : -30.f;
        const float p = __builtin_amdgcn_exp2f(e) * linv[r];
        psf[wave * 1024 + (gq * 4 + r) * 64 + nt * 16 + c] = p;
      }
    }
#pragma unroll
    for (int ks = 0; ks < 2; ++ks) {
      const float4 f0 = *(const float4*)&psf[wave * 1024 + c * 64 + ks * 32 + gq * 8];
      const float4 f1 = *(const float4*)&psf[wave * 1024 + c * 64 + ks * 32 + gq * 8 + 4];
      unsigned short pr[8] = {f2bf(f0.x), f2bf(f0.y), f2bf(f0.z), f2bf(f0.w),
                              f2bf(f1.x), f2bf(f1.y), f2bf(f1.z), f2bf(f1.w)};
      const short8 ap = *(const short8*)pr;
      __builtin_amdgcn_s_setprio(1);
#pragma unroll
      for (int nt = 0; nt < 4; ++nt) {
        const short8 bv = *(const short8*)&vt[buf][(nt * 16 + c) * 64 + rdcol(ks)];
        o[nt] = mfma_bf16(ap, bv, o[nt]);
      }
      __builtin_amdgcn_s_setprio(0);
    }
#pragma unroll
    for (int pass = 0; pass < 4; ++pass) {
      const int row = pass * 4 + (lane >> 4);
      const int col4 = lane & 15;
      const float4 pv = *(const float4*)&psf[wave * 1024 + row * 64 + col4 * 4];
      *(float4*)&att[((long)((b * 16 + h) * 2048 + q0 + wave * 16 + row)) * 2048 +
                     kv * 64 + col4 * 4] = pv;
    }
    asm volatile("s_waitcnt lgkmcnt(0)" ::: "memory");
    __builtin_amdgcn_s_barrier();
    __builtin_amdgcn_sched_barrier(0);
    buf ^= 1;
  }

#pragma unroll
  for (int nt = 0; nt < 4; ++nt)
#pragma unroll
    for (int r = 0; r < 4; ++r) {
      const int row = q0 + wave * 16 + gq * 4 + r;
      Obuf[(b * 2048 + row) * 1024 + h * 64 + nt * 16 + c] = f2bf(o[nt][r]);
    }
}

// ---------------------------------------------------------------------------
extern "C" void kernel_launch(void* const* d_in, const int* in_sizes, int n_in,
                              void* d_out, int out_size, void* d_ws, size_t ws_size,
                              hipStream_t stream) {
  const float* query = (const float*)d_in[0];
  const float* key   = (const float*)d_in[1];
  const float* value = (const float*)d_in[2];
  const int* mask    = (const int*)d_in[3];
  const float* Wq = (const float*)d_in[4];
  const float* bq = (const float*)d_in[5];
  const float* Wk = (const float*)d_in[6];
  const float* bk = (const float*)d_in[7];
  const float* Wv = (const float*)d_in[8];
  const float* bv = (const float*)d_in[9];
  const float* Wo = (const float*)d_in[10];
  const float* bo = (const float*)d_in[11];

  float* out = (float*)d_out;
  float* att = out + 4194304;  // B*S*D fp32, then B*H*S*S fp32

  char* ws = (char*)d_ws;
  const size_t MB = 1u << 20;
  unsigned short* Aq   = (unsigned short*)(ws);            // bf16 query
  unsigned short* Ak   = (unsigned short*)(ws + 8 * MB);   // bf16 key
  unsigned short* Av   = (unsigned short*)(ws + 16 * MB);  // bf16 value
  unsigned short* Qb   = (unsigned short*)(ws + 24 * MB);
  unsigned short* Kb   = (unsigned short*)(ws + 32 * MB);
  unsigned short* Vt   = (unsigned short*)(ws + 40 * MB);
  unsigned short* Obuf = (unsigned short*)(ws + 48 * MB);
  unsigned short* WqT  = (unsigned short*)(ws + 56 * MB);
  unsigned short* WkT  = (unsigned short*)(ws + 58 * MB);
  unsigned short* WvT  = (unsigned short*)(ws + 60 * MB);
  unsigned short* WoT  = (unsigned short*)(ws + 62 * MB);
  unsigned long long* mbits = (unsigned long long*)(ws + 64 * MB);

  conv_f32_bf16<<<dim3(2048, 1, 3), 256, 0, stream>>>(query, key, value, Aq, Ak, Av);
  transpose_w<<<dim3(16, 16, 4), 256, 0, stream>>>(Wq, Wk, Wv, Wo, WqT, WkT, WvT, WoT);
  mask_prep<<<dim3(512), 256, 0, stream>>>(mask, mbits);

  GArg gq{Aq, WqT, bq, Qb, 0};
  GArg gk{Ak, WkT, bk, Kb, 0};
  GArg gv{Av, WvT, bv, Vt, 1};
  gemm_bt<<<dim3(8, 32, 3), 256, 0, stream>>>(gq, gk, gv);

  attn_kern<<<dim3(32, 16, 2), 256, 0, stream>>>(Qb, Kb, Vt, mbits, att, Obuf);
  // ---- diagnostic: 2 extra idempotent attn launches (attn = (dur-837)/2) --
  attn_kern<<<dim3(32, 16, 2), 256, 0, stream>>>(Qb, Kb, Vt, mbits, att, Obuf);
  attn_kern<<<dim3(32, 16, 2), 256, 0, stream>>>(Qb, Kb, Vt, mbits, att, Obuf);

  GArg go{Obuf, WoT, bo, out, 2};
  gemm_bt<<<dim3(8, 32, 1), 256, 0, stream>>>(go, go, go);
}

// Round 5
// 832.803 us; speedup vs baseline: 1.4843x; 1.4843x over previous
//
#include <hip/hip_runtime.h>
#include <stdint.h>

// ---------------------------------------------------------------------------
// MHA fwd: B=2,S=2048,D=1024,H=16,DK=DV=64. fp32 I/O, bf16 MFMA, fp32 accum.
// out = softmax(mask(QK^T/8)) @ V @ Wo + bo ; also returns attention matrix.
//
// Budget (measured, rounds 3-4): harness overhead ~497us, attn ~200us,
// GEMMs+preps ~140us. This round: attn restructure for 4 blocks/CU + less
// LDS traffic. Target attn ~120us.
// ---------------------------------------------------------------------------

typedef __attribute__((ext_vector_type(8))) __bf16 bf16x8;
typedef __attribute__((ext_vector_type(8))) short short8;
typedef __attribute__((ext_vector_type(4))) float f32x4;

static __device__ __forceinline__ f32x4 mfma_bf16(short8 a, short8 b, f32x4 c) {
  return __builtin_amdgcn_mfma_f32_16x16x32_bf16(
      __builtin_bit_cast(bf16x8, a), __builtin_bit_cast(bf16x8, b), c, 0, 0, 0);
}

static __device__ __forceinline__ unsigned short f2bf(float f) {
  unsigned int u = __float_as_uint(f);
  u += 0x7fffu + ((u >> 16) & 1u);           // round-to-nearest-even
  return (unsigned short)(u >> 16);
}

// global->LDS direct copy, 16B per lane. LDS dest is wave-uniform base + lane*16.
static __device__ __forceinline__ void gload_lds16(const void* g, void* l) {
  __builtin_amdgcn_global_load_lds(
      (__attribute__((address_space(1))) void*)(uintptr_t)(g),
      (__attribute__((address_space(3))) void*)(uintptr_t)(l), 16, 0, 0);
}

// ---------------------------------------------------------------------------
// fp32 -> bf16 conversion for query/key/value activations. 8 floats/thread.
// ---------------------------------------------------------------------------
__global__ __launch_bounds__(256) void conv_f32_bf16(
    const float* q, const float* k, const float* v,
    unsigned short* oq, unsigned short* ok, unsigned short* ov) {
  const float* src = (blockIdx.z == 0) ? q : (blockIdx.z == 1) ? k : v;
  unsigned short* dst = (blockIdx.z == 0) ? oq : (blockIdx.z == 1) ? ok : ov;
  const int i = (blockIdx.x * 256 + threadIdx.x) * 8;
  const float4 a = *(const float4*)&src[i];
  const float4 b = *(const float4*)&src[i + 4];
  unsigned short r[8] = {f2bf(a.x), f2bf(a.y), f2bf(a.z), f2bf(a.w),
                         f2bf(b.x), f2bf(b.y), f2bf(b.z), f2bf(b.w)};
  *(uint4*)&dst[i] = *(uint4*)r;
}

// ---------------------------------------------------------------------------
// Weight transpose+convert: WT[n][k] = bf16(W[k][n]), 1024x1024, z = matrix.
// ---------------------------------------------------------------------------
__global__ __launch_bounds__(256) void transpose_w(
    const float* w0, const float* w1, const float* w2, const float* w3,
    unsigned short* o0, unsigned short* o1,
    unsigned short* o2, unsigned short* o3) {
  const float* src = (blockIdx.z == 0) ? w0 : (blockIdx.z == 1) ? w1
                                         : (blockIdx.z == 2) ? w2 : w3;
  unsigned short* dst = (blockIdx.z == 0) ? o0 : (blockIdx.z == 1) ? o1
                                           : (blockIdx.z == 2) ? o2 : o3;
  __shared__ unsigned short tile[64 * 66];
  const int t = threadIdx.x;
  const int r0 = blockIdx.y * 64, c0 = blockIdx.x * 64;
#pragma unroll
  for (int i = 0; i < 4; ++i) {
    const int slot = i * 256 + t;
    const int row = slot >> 4, cg = slot & 15;
    const float4 v = *(const float4*)&src[(r0 + row) * 1024 + c0 + cg * 4];
    unsigned int p0 = (unsigned int)f2bf(v.x) | ((unsigned int)f2bf(v.y) << 16);
    unsigned int p1 = (unsigned int)f2bf(v.z) | ((unsigned int)f2bf(v.w) << 16);
    unsigned int* dp = (unsigned int*)&tile[row * 66 + cg * 4];
    dp[0] = p0;
    dp[1] = p1;
  }
  __syncthreads();
#pragma unroll
  for (int i = 0; i < 2; ++i) {
    const int slot = i * 256 + t;
    const int orow = slot >> 3, kg = slot & 7;
    unsigned short vals[8];
#pragma unroll
    for (int j = 0; j < 8; ++j) vals[j] = tile[(kg * 8 + j) * 66 + orow];
    *(uint4*)&dst[(c0 + orow) * 1024 + r0 + kg * 8] = *(uint4*)vals;
  }
}

// ---------------------------------------------------------------------------
// Pack mask into bitmask: bits[w] bit L = (mask[w*64+L] != 0).  131072 words.
// ---------------------------------------------------------------------------
__global__ __launch_bounds__(256) void mask_prep(const int* __restrict__ mask,
                                                 unsigned long long* __restrict__ bits) {
  const int wid = (blockIdx.x * 256 + threadIdx.x) >> 6;  // 2048 waves
  const int lane = threadIdx.x & 63;
  for (int w = wid; w < 131072; w += 2048) {
    const int m = mask[w * 64 + lane];
    const unsigned long long b = __ballot(m != 0);
    if (lane == 0) bits[w] = b;
  }
}

// ---------------------------------------------------------------------------
// GEMM: C[4096,1024] = A[4096,1024](bf16) @ BT[1024,1024]^T(bf16) + bias(f32).
// mode 0: bf16 row-major store. mode 1: bf16 V head-transpose Vt[b][col][s].
// mode 2: fp32 row-major store (final output).
// ---------------------------------------------------------------------------
struct GArg {
  const unsigned short* A;
  const unsigned short* BT;
  const float* bias;
  void* C;
  int mode;
};

__global__ __launch_bounds__(256) void gemm_bt(GArg ga, GArg gb, GArg gc) {
  const GArg g = (blockIdx.z == 0) ? ga : (blockIdx.z == 1) ? gb : gc;
  __shared__ alignas(16) unsigned short ash[128 * 64];
  __shared__ alignas(16) unsigned short bsh[128 * 64];
  const int t = threadIdx.x;
  const int wave = t >> 6, lane = t & 63;
  const int m0 = blockIdx.y * 128, n0 = blockIdx.x * 128;
  const int wm = (wave >> 1) * 64, wn = (wave & 1) * 64;
  const int c = lane & 15, gq = lane >> 4;
  const int srow = wave * 8 + (lane >> 3);
  const int scol = (lane & 7) * 8;

  f32x4 zero = {0.f, 0.f, 0.f, 0.f};
  f32x4 acc[4][4];
#pragma unroll
  for (int i = 0; i < 4; ++i)
#pragma unroll
    for (int j = 0; j < 4; ++j) acc[i][j] = zero;

  for (int kk = 0; kk < 16; ++kk) {
    __syncthreads();
    const int kbase = kk * 64;
#pragma unroll
    for (int i = 0; i < 4; ++i) {
      gload_lds16(&g.A[(m0 + i * 32 + srow) * 1024 + kbase + scol],
                  &ash[(i * 32 + wave * 8) * 64]);
      gload_lds16(&g.BT[(n0 + i * 32 + srow) * 1024 + kbase + scol],
                  &bsh[(i * 32 + wave * 8) * 64]);
    }
    __syncthreads();
#pragma unroll
    for (int ks = 0; ks < 2; ++ks) {
      short8 af[4], bf[4];
#pragma unroll
      for (int mt = 0; mt < 4; ++mt)
        af[mt] = *(const short8*)&ash[(wm + mt * 16 + c) * 64 + ks * 32 + gq * 8];
#pragma unroll
      for (int nt = 0; nt < 4; ++nt)
        bf[nt] = *(const short8*)&bsh[(wn + nt * 16 + c) * 64 + ks * 32 + gq * 8];
#pragma unroll
      for (int mt = 0; mt < 4; ++mt)
#pragma unroll
        for (int nt = 0; nt < 4; ++nt)
          acc[mt][nt] = mfma_bf16(af[mt], bf[nt], acc[mt][nt]);
    }
  }
#pragma unroll
  for (int nt = 0; nt < 4; ++nt) {
    const int gcol = n0 + wn + nt * 16 + c;
    const float bia = g.bias[gcol];
#pragma unroll
    for (int mt = 0; mt < 4; ++mt) {
#pragma unroll
      for (int r = 0; r < 4; ++r) {
        const int grow = m0 + wm + mt * 16 + gq * 4 + r;
        const float v = acc[mt][nt][r] + bia;
        if (g.mode == 0) {
          ((unsigned short*)g.C)[grow * 1024 + gcol] = f2bf(v);
        } else if (g.mode == 1) {  // Vt[b][gcol][s]
          ((unsigned short*)g.C)[((grow >> 11) << 21) + (gcol << 11) + (grow & 2047)] =
              f2bf(v);
        } else {  // fp32 row-major (final out)
          ((float*)g.C)[grow * 1024 + gcol] = v;
        }
      }
    }
  }
}

// ---------------------------------------------------------------------------
// Attention v3: per block = (qtile 64 rows, head, batch). 4 waves x 16 q-rows.
//
// LDS 40KB (kt 16 + vt 16 + psfb 8) -> 4 blocks/CU; grid 1024 = 4x256 exact.
// psfb: per-wave [16][64] bf16, XOR-swizzled cols (col ^= (row&7)<<3) -> the
// P-transpose for the PV A-operand costs 16 ds_write_b16 + 4 ds_read_b128.
// att is stored DIRECTLY from s-layout fp32 regs: 16 global_store_dword,
// lanes (c,gq) cover 4 rows x 64B contiguous each -> coalesced.
// Counted waits re-derived for 16 stores/iter: steady [L_kv(4), S(16),
// L_next(4)] -> vmcnt(20); last iter vmcnt(16). (Round-4 passing vmcnt(8)
// proved the queue has no compiler-injected vmem ops.)
// ---------------------------------------------------------------------------
__global__ __launch_bounds__(256, 4) void attn_kern(
    const unsigned short* __restrict__ Qb, const unsigned short* __restrict__ Kb,
    const unsigned short* __restrict__ Vt, const unsigned long long* __restrict__ mbits,
    float* __restrict__ att, unsigned short* __restrict__ Obuf) {
  const int id0 = blockIdx.x + 32 * (blockIdx.y + 16 * blockIdx.z);
  const int id = (id0 & 7) * 128 + (id0 >> 3);
  const int qt = id & 31, h = (id >> 5) & 15, b = id >> 9;
  const int t = threadIdx.x, wave = t >> 6, lane = t & 63;
  const int q0 = qt * 64;
  const int c = lane & 15, gq = lane >> 4;
  const int srow = lane >> 3;                       // 0..7
  const int scol_sw = ((lane & 7) ^ srow) * 8;      // pre-swizzled source col
  const float SCALE = 0.125f * 1.44269504088896341f;  // (1/8)*log2(e)

  __shared__ alignas(16) unsigned short kt[2][64 * 64];   // 16 KB
  __shared__ alignas(16) unsigned short vt[2][64 * 64];   // 16 KB
  __shared__ alignas(16) unsigned short psfb[4][16 * 64]; // 8 KB bf16 P

  auto stage_k = [&](int kvt, int bu) {
#pragma unroll
    for (int i = 0; i < 2; ++i)
      gload_lds16(&Kb[(b * 2048 + kvt * 64 + wave * 16 + i * 8 + srow) * 1024 +
                      h * 64 + scol_sw],
                  &kt[bu][(wave * 16 + i * 8) * 64]);
  };
  auto stage_v = [&](int kvt, int bu) {
#pragma unroll
    for (int i = 0; i < 2; ++i)
      gload_lds16(&Vt[(b << 21) + (h * 64 + wave * 16 + i * 8 + srow) * 2048 +
                      kvt * 64 + scol_sw],
                  &vt[bu][(wave * 16 + i * 8) * 64]);
  };
  auto rdcol = [&](int ks) { return (((ks * 4 + gq) ^ (c & 7)) * 8); };

  stage_k(0, 0);

  // mask staging via vt region (dead until phase-2 prologue). Each wave
  // writes & reads only its own 16 rows -> wave-local in-order DS.
  unsigned long long* msk = (unsigned long long*)vt;  // [64][32]
  {
    const int row = t >> 2, c8 = (t & 3) * 8;
    const unsigned long long* src = &mbits[(unsigned)(b * 2048 + q0 + row) * 32 + c8];
#pragma unroll
    for (int j = 0; j < 8; ++j) msk[row * 32 + c8 + j] = src[j];
  }
  __builtin_amdgcn_sched_barrier(0);
  unsigned long long mlo[4], mhi[4];
#pragma unroll
  for (int r = 0; r < 4; ++r) {
    const int row = wave * 16 + gq * 4 + r;
    unsigned long long lo = 0, hi = 0;
#pragma unroll
    for (int kvi = 0; kvi < 16; ++kvi) {
      const unsigned long long w0 = msk[row * 32 + kvi] >> c;
      const unsigned long long w1 = msk[row * 32 + 16 + kvi] >> c;
      const unsigned long long n0 =
          (w0 & 1) | ((w0 >> 15) & 2) | ((w0 >> 30) & 4) | ((w0 >> 45) & 8);
      const unsigned long long n1 =
          (w1 & 1) | ((w1 >> 15) & 2) | ((w1 >> 30) & 4) | ((w1 >> 45) & 8);
      lo |= n0 << (kvi * 4);
      hi |= n1 << (kvi * 4);
    }
    mlo[r] = lo;
    mhi[r] = hi;
  }

  short8 aq[2];
  {
    const unsigned short* qrow = &Qb[(b * 2048 + q0 + wave * 16 + c) * 1024 + h * 64];
    aq[0] = *(const short8*)&qrow[gq * 8];
    aq[1] = *(const short8*)&qrow[32 + gq * 8];
  }

  asm volatile("s_waitcnt vmcnt(0) lgkmcnt(0)" ::: "memory");
  __builtin_amdgcn_s_barrier();
  __builtin_amdgcn_sched_barrier(0);

  const f32x4 zero = {0.f, 0.f, 0.f, 0.f};
  float lsum[4] = {0.f, 0.f, 0.f, 0.f};
  int buf = 0;

  // ---- phase 1: row sums of 2^e' ----
#pragma unroll 1
  for (int kv = 0; kv < 32; ++kv) {
    if (kv < 31) {
      stage_k(kv + 1, buf ^ 1);
      asm volatile("s_waitcnt vmcnt(2)" ::: "memory");
    } else {
      asm volatile("s_waitcnt vmcnt(0)" ::: "memory");
    }
    __builtin_amdgcn_s_barrier();
    __builtin_amdgcn_sched_barrier(0);

    f32x4 s[4];
#pragma unroll
    for (int nt = 0; nt < 4; ++nt) s[nt] = zero;
    __builtin_amdgcn_s_setprio(1);
#pragma unroll
    for (int ks = 0; ks < 2; ++ks)
#pragma unroll
      for (int nt = 0; nt < 4; ++nt) {
        const short8 bk = *(const short8*)&kt[buf][(nt * 16 + c) * 64 + rdcol(ks)];
        s[nt] = mfma_bf16(aq[ks], bk, s[nt]);
      }
    __builtin_amdgcn_s_setprio(0);
#pragma unroll
    for (int r = 0; r < 4; ++r) {
      const unsigned long long mr = (kv < 16) ? mlo[r] : mhi[r];
      const unsigned nib = (unsigned)(mr >> ((kv & 15) * 4)) & 0xFu;
#pragma unroll
      for (int nt = 0; nt < 4; ++nt) {
        const float e = ((nib >> nt) & 1u) ? s[nt][r] * SCALE : -30.f;
        lsum[r] += __builtin_amdgcn_exp2f(e);
      }
    }
    asm volatile("s_waitcnt lgkmcnt(0)" ::: "memory");
    __builtin_amdgcn_s_barrier();
    __builtin_amdgcn_sched_barrier(0);
    buf ^= 1;
  }

  float linv[4];
#pragma unroll
  for (int r = 0; r < 4; ++r) {
    float v = lsum[r];
    v += __shfl_xor(v, 1);
    v += __shfl_xor(v, 2);
    v += __shfl_xor(v, 4);
    v += __shfl_xor(v, 8);
    linv[r] = 1.0f / v;
  }

  f32x4 o[4];
#pragma unroll
  for (int nt = 0; nt < 4; ++nt) o[nt] = zero;

  // ---- phase 2 prologue: stage K0+V0 (buf == 0 after 32 toggles) ----
  stage_k(0, buf);
  stage_v(0, buf);
  asm volatile("s_waitcnt vmcnt(0)" ::: "memory");
  __builtin_amdgcn_s_barrier();
  __builtin_amdgcn_sched_barrier(0);

  // att row bases: row = q0+wave*16+gq*4+r, starting col = c; advance 64/iter.
  float* attb[4];
#pragma unroll
  for (int r = 0; r < 4; ++r)
    attb[r] = att + (long)((b * 16 + h) * 2048 + q0 + wave * 16 + gq * 4 + r) * 2048 + c;

  unsigned short* pw = &psfb[wave][0];

  // ---- phase 2: store fp32 attention from regs, accumulate O = P @ V ----
#pragma unroll 1
  for (int kv = 0; kv < 32; ++kv) {
    if (kv < 31) {
      stage_k(kv + 1, buf ^ 1);
      stage_v(kv + 1, buf ^ 1);
      // queue: [L_kv(4), S_{kv-1}(16), L_{kv+1}(4)] -> vmcnt(20) retires L_kv.
      asm volatile("s_waitcnt vmcnt(20)" ::: "memory");
    } else {
      // queue: [L_31(4), S_30(16)] -> vmcnt(16) retires L_31.
      asm volatile("s_waitcnt vmcnt(16)" ::: "memory");
    }
    __builtin_amdgcn_s_barrier();
    __builtin_amdgcn_sched_barrier(0);

    f32x4 s[4];
#pragma unroll
    for (int nt = 0; nt < 4; ++nt) s[nt] = zero;
    __builtin_amdgcn_s_setprio(1);
#pragma unroll
    for (int ks = 0; ks < 2; ++ks)
#pragma unroll
      for (int nt = 0; nt < 4; ++nt) {
        const short8 bk = *(const short8*)&kt[buf][(nt * 16 + c) * 64 + rdcol(ks)];
        s[nt] = mfma_bf16(aq[ks], bk, s[nt]);
      }
    __builtin_amdgcn_s_setprio(0);

    // p = exp2(e)*linv: store att directly (coalesced 4 rows x 64B per instr),
    // and write bf16 P to psfb (XOR-swizzled) for the PV A-operand.
#pragma unroll
    for (int r = 0; r < 4; ++r) {
      const unsigned long long mr = (kv < 16) ? mlo[r] : mhi[r];
      const unsigned nib = (unsigned)(mr >> ((kv & 15) * 4)) & 0xFu;
      const int prow = gq * 4 + r;
      const int sw = (prow & 7) << 3;
#pragma unroll
      for (int nt = 0; nt < 4; ++nt) {
        const float e = ((nib >> nt) & 1u) ? s[nt][r] * SCALE : -30.f;
        const float p = __builtin_amdgcn_exp2f(e) * linv[r];
        attb[r][nt * 16] = p;                                // global dword
        pw[prow * 64 + ((nt * 16 + c) ^ sw)] = f2bf(p);      // ds_write_b16
      }
      attb[r] += 64;
    }
    __builtin_amdgcn_sched_barrier(0);  // pin psfb writes before A-read

    // PV accumulate: A-frag direct from psfb (bf16, swizzled), wave-local.
#pragma unroll
    for (int ks = 0; ks < 2; ++ks) {
      const short8 ap =
          *(const short8*)&pw[c * 64 + ((ks * 32 + gq * 8) ^ ((c & 7) << 3))];
      __builtin_amdgcn_s_setprio(1);
#pragma unroll
      for (int nt = 0; nt < 4; ++nt) {
        const short8 bv = *(const short8*)&vt[buf][(nt * 16 + c) * 64 + rdcol(ks)];
        o[nt] = mfma_bf16(ap, bv, o[nt]);
      }
      __builtin_amdgcn_s_setprio(0);
    }
    asm volatile("s_waitcnt lgkmcnt(0)" ::: "memory");  // kt/vt/psfb reads done
    __builtin_amdgcn_s_barrier();
    __builtin_amdgcn_sched_barrier(0);
    buf ^= 1;
  }

  // store O (bf16) in [B,S,H*DV]
#pragma unroll
  for (int nt = 0; nt < 4; ++nt)
#pragma unroll
    for (int r = 0; r < 4; ++r) {
      const int row = q0 + wave * 16 + gq * 4 + r;
      Obuf[(b * 2048 + row) * 1024 + h * 64 + nt * 16 + c] = f2bf(o[nt][r]);
    }
}

// ---------------------------------------------------------------------------
extern "C" void kernel_launch(void* const* d_in, const int* in_sizes, int n_in,
                              void* d_out, int out_size, void* d_ws, size_t ws_size,
                              hipStream_t stream) {
  const float* query = (const float*)d_in[0];
  const float* key   = (const float*)d_in[1];
  const float* value = (const float*)d_in[2];
  const int* mask    = (const int*)d_in[3];
  const float* Wq = (const float*)d_in[4];
  const float* bq = (const float*)d_in[5];
  const float* Wk = (const float*)d_in[6];
  const float* bk = (const float*)d_in[7];
  const float* Wv = (const float*)d_in[8];
  const float* bv = (const float*)d_in[9];
  const float* Wo = (const float*)d_in[10];
  const float* bo = (const float*)d_in[11];

  float* out = (float*)d_out;
  float* att = out + 4194304;  // B*S*D fp32, then B*H*S*S fp32

  char* ws = (char*)d_ws;
  const size_t MB = 1u << 20;
  unsigned short* Aq   = (unsigned short*)(ws);            // bf16 query
  unsigned short* Ak   = (unsigned short*)(ws + 8 * MB);   // bf16 key
  unsigned short* Av   = (unsigned short*)(ws + 16 * MB);  // bf16 value
  unsigned short* Qb   = (unsigned short*)(ws + 24 * MB);
  unsigned short* Kb   = (unsigned short*)(ws + 32 * MB);
  unsigned short* Vt   = (unsigned short*)(ws + 40 * MB);
  unsigned short* Obuf = (unsigned short*)(ws + 48 * MB);
  unsigned short* WqT  = (unsigned short*)(ws + 56 * MB);
  unsigned short* WkT  = (unsigned short*)(ws + 58 * MB);
  unsigned short* WvT  = (unsigned short*)(ws + 60 * MB);
  unsigned short* WoT  = (unsigned short*)(ws + 62 * MB);
  unsigned long long* mbits = (unsigned long long*)(ws + 64 * MB);

  conv_f32_bf16<<<dim3(2048, 1, 3), 256, 0, stream>>>(query, key, value, Aq, Ak, Av);
  transpose_w<<<dim3(16, 16, 4), 256, 0, stream>>>(Wq, Wk, Wv, Wo, WqT, WkT, WvT, WoT);
  mask_prep<<<dim3(512), 256, 0, stream>>>(mask, mbits);

  GArg gq{Aq, WqT, bq, Qb, 0};
  GArg gk{Ak, WkT, bk, Kb, 0};
  GArg gv{Av, WvT, bv, Vt, 1};
  gemm_bt<<<dim3(8, 32, 3), 256, 0, stream>>>(gq, gk, gv);

  attn_kern<<<dim3(32, 16, 2), 256, 0, stream>>>(Qb, Kb, Vt, mbits, att, Obuf);

  GArg go{Obuf, WoT, bo, out, 2};
  gemm_bt<<<dim3(8, 32, 1), 256, 0, stream>>>(go, go, go);
}

// Round 6
// 820.891 us; speedup vs baseline: 1.5058x; 1.0145x over previous
//
#include <hip/hip_runtime.h>
#include <stdint.h>

// ---------------------------------------------------------------------------
// MHA fwd: B=2,S=2048,D=1024,H=16,DK=DV=64. fp32 I/O, bf16 MFMA, fp32 accum.
// out = softmax(mask(QK^T/8)) @ V @ Wo + bo ; also returns attention matrix.
//
// Budget (measured, rounds 3-5): harness overhead ~497us, attn ~195us,
// GEMMs+preps ~140us. Round-5 null result (occupancy/LDS restructure = -4us)
// localized attn's excess to memory stall: 536MB of att stores thrash the
// per-XCD L2 (K/V working set = 4MB = L2 size), forcing ~1.5GB of K/V HBM
// re-reads. This round: NON-TEMPORAL att stores (no-allocate in L2) so K/V
// stays L2-resident. Target attn ~130us.
// ---------------------------------------------------------------------------

typedef __attribute__((ext_vector_type(8))) __bf16 bf16x8;
typedef __attribute__((ext_vector_type(8))) short short8;
typedef __attribute__((ext_vector_type(4))) float f32x4;

static __device__ __forceinline__ f32x4 mfma_bf16(short8 a, short8 b, f32x4 c) {
  return __builtin_amdgcn_mfma_f32_16x16x32_bf16(
      __builtin_bit_cast(bf16x8, a), __builtin_bit_cast(bf16x8, b), c, 0, 0, 0);
}

static __device__ __forceinline__ unsigned short f2bf(float f) {
  unsigned int u = __float_as_uint(f);
  u += 0x7fffu + ((u >> 16) & 1u);           // round-to-nearest-even
  return (unsigned short)(u >> 16);
}

// global->LDS direct copy, 16B per lane. LDS dest is wave-uniform base + lane*16.
static __device__ __forceinline__ void gload_lds16(const void* g, void* l) {
  __builtin_amdgcn_global_load_lds(
      (__attribute__((address_space(1))) void*)(uintptr_t)(g),
      (__attribute__((address_space(3))) void*)(uintptr_t)(l), 16, 0, 0);
}

// ---------------------------------------------------------------------------
// fp32 -> bf16 conversion for query/key/value activations. 8 floats/thread.
// ---------------------------------------------------------------------------
__global__ __launch_bounds__(256) void conv_f32_bf16(
    const float* q, const float* k, const float* v,
    unsigned short* oq, unsigned short* ok, unsigned short* ov) {
  const float* src = (blockIdx.z == 0) ? q : (blockIdx.z == 1) ? k : v;
  unsigned short* dst = (blockIdx.z == 0) ? oq : (blockIdx.z == 1) ? ok : ov;
  const int i = (blockIdx.x * 256 + threadIdx.x) * 8;
  const float4 a = *(const float4*)&src[i];
  const float4 b = *(const float4*)&src[i + 4];
  unsigned short r[8] = {f2bf(a.x), f2bf(a.y), f2bf(a.z), f2bf(a.w),
                         f2bf(b.x), f2bf(b.y), f2bf(b.z), f2bf(b.w)};
  *(uint4*)&dst[i] = *(uint4*)r;
}

// ---------------------------------------------------------------------------
// Weight transpose+convert: WT[n][k] = bf16(W[k][n]), 1024x1024, z = matrix.
// ---------------------------------------------------------------------------
__global__ __launch_bounds__(256) void transpose_w(
    const float* w0, const float* w1, const float* w2, const float* w3,
    unsigned short* o0, unsigned short* o1,
    unsigned short* o2, unsigned short* o3) {
  const float* src = (blockIdx.z == 0) ? w0 : (blockIdx.z == 1) ? w1
                                         : (blockIdx.z == 2) ? w2 : w3;
  unsigned short* dst = (blockIdx.z == 0) ? o0 : (blockIdx.z == 1) ? o1
                                           : (blockIdx.z == 2) ? o2 : o3;
  __shared__ unsigned short tile[64 * 66];
  const int t = threadIdx.x;
  const int r0 = blockIdx.y * 64, c0 = blockIdx.x * 64;
#pragma unroll
  for (int i = 0; i < 4; ++i) {
    const int slot = i * 256 + t;
    const int row = slot >> 4, cg = slot & 15;
    const float4 v = *(const float4*)&src[(r0 + row) * 1024 + c0 + cg * 4];
    unsigned int p0 = (unsigned int)f2bf(v.x) | ((unsigned int)f2bf(v.y) << 16);
    unsigned int p1 = (unsigned int)f2bf(v.z) | ((unsigned int)f2bf(v.w) << 16);
    unsigned int* dp = (unsigned int*)&tile[row * 66 + cg * 4];
    dp[0] = p0;
    dp[1] = p1;
  }
  __syncthreads();
#pragma unroll
  for (int i = 0; i < 2; ++i) {
    const int slot = i * 256 + t;
    const int orow = slot >> 3, kg = slot & 7;
    unsigned short vals[8];
#pragma unroll
    for (int j = 0; j < 8; ++j) vals[j] = tile[(kg * 8 + j) * 66 + orow];
    *(uint4*)&dst[(c0 + orow) * 1024 + r0 + kg * 8] = *(uint4*)vals;
  }
}

// ---------------------------------------------------------------------------
// Pack mask into bitmask: bits[w] bit L = (mask[w*64+L] != 0).  131072 words.
// ---------------------------------------------------------------------------
__global__ __launch_bounds__(256) void mask_prep(const int* __restrict__ mask,
                                                 unsigned long long* __restrict__ bits) {
  const int wid = (blockIdx.x * 256 + threadIdx.x) >> 6;  // 2048 waves
  const int lane = threadIdx.x & 63;
  for (int w = wid; w < 131072; w += 2048) {
    const int m = mask[w * 64 + lane];
    const unsigned long long b = __ballot(m != 0);
    if (lane == 0) bits[w] = b;
  }
}

// ---------------------------------------------------------------------------
// GEMM: C[4096,1024] = A[4096,1024](bf16) @ BT[1024,1024]^T(bf16) + bias(f32).
// mode 0: bf16 row-major store. mode 1: bf16 V head-transpose Vt[b][col][s].
// mode 2: fp32 row-major store (final output, non-temporal).
// ---------------------------------------------------------------------------
struct GArg {
  const unsigned short* A;
  const unsigned short* BT;
  const float* bias;
  void* C;
  int mode;
};

__global__ __launch_bounds__(256) void gemm_bt(GArg ga, GArg gb, GArg gc) {
  const GArg g = (blockIdx.z == 0) ? ga : (blockIdx.z == 1) ? gb : gc;
  __shared__ alignas(16) unsigned short ash[128 * 64];
  __shared__ alignas(16) unsigned short bsh[128 * 64];
  const int t = threadIdx.x;
  const int wave = t >> 6, lane = t & 63;
  const int m0 = blockIdx.y * 128, n0 = blockIdx.x * 128;
  const int wm = (wave >> 1) * 64, wn = (wave & 1) * 64;
  const int c = lane & 15, gq = lane >> 4;
  const int srow = wave * 8 + (lane >> 3);
  const int scol = (lane & 7) * 8;

  f32x4 zero = {0.f, 0.f, 0.f, 0.f};
  f32x4 acc[4][4];
#pragma unroll
  for (int i = 0; i < 4; ++i)
#pragma unroll
    for (int j = 0; j < 4; ++j) acc[i][j] = zero;

  for (int kk = 0; kk < 16; ++kk) {
    __syncthreads();
    const int kbase = kk * 64;
#pragma unroll
    for (int i = 0; i < 4; ++i) {
      gload_lds16(&g.A[(m0 + i * 32 + srow) * 1024 + kbase + scol],
                  &ash[(i * 32 + wave * 8) * 64]);
      gload_lds16(&g.BT[(n0 + i * 32 + srow) * 1024 + kbase + scol],
                  &bsh[(i * 32 + wave * 8) * 64]);
    }
    __syncthreads();
#pragma unroll
    for (int ks = 0; ks < 2; ++ks) {
      short8 af[4], bf[4];
#pragma unroll
      for (int mt = 0; mt < 4; ++mt)
        af[mt] = *(const short8*)&ash[(wm + mt * 16 + c) * 64 + ks * 32 + gq * 8];
#pragma unroll
      for (int nt = 0; nt < 4; ++nt)
        bf[nt] = *(const short8*)&bsh[(wn + nt * 16 + c) * 64 + ks * 32 + gq * 8];
#pragma unroll
      for (int mt = 0; mt < 4; ++mt)
#pragma unroll
        for (int nt = 0; nt < 4; ++nt)
          acc[mt][nt] = mfma_bf16(af[mt], bf[nt], acc[mt][nt]);
    }
  }
#pragma unroll
  for (int nt = 0; nt < 4; ++nt) {
    const int gcol = n0 + wn + nt * 16 + c;
    const float bia = g.bias[gcol];
#pragma unroll
    for (int mt = 0; mt < 4; ++mt) {
#pragma unroll
      for (int r = 0; r < 4; ++r) {
        const int grow = m0 + wm + mt * 16 + gq * 4 + r;
        const float v = acc[mt][nt][r] + bia;
        if (g.mode == 0) {
          ((unsigned short*)g.C)[grow * 1024 + gcol] = f2bf(v);
        } else if (g.mode == 1) {  // Vt[b][gcol][s]
          ((unsigned short*)g.C)[((grow >> 11) << 21) + (gcol << 11) + (grow & 2047)] =
              f2bf(v);
        } else {  // fp32 row-major final out: write-once, never re-read -> nt
          __builtin_nontemporal_store(v, &((float*)g.C)[grow * 1024 + gcol]);
        }
      }
    }
  }
}

// ---------------------------------------------------------------------------
// Attention v3+nt: per block = (qtile 64 rows, head, batch). 4 waves x 16 q-rows.
//
// LDS 40KB (kt 16 + vt 16 + psfb 8) -> 4 blocks/CU; grid 1024 = 4x256 exact.
// att is stored DIRECTLY from s-layout fp32 regs via NON-TEMPORAL
// global_store_dword (no L2 allocate): keeps the per-XCD K/V working set
// (4 heads x 1MB = 4MB = L2 size) resident, so the double-buffered staging
// loads hit L2 instead of re-fetching ~1.5GB from HBM (round-5 diagnosis).
// Counted waits: steady [L_kv(4), S(16), L_next(4)] -> vmcnt(20); last iter
// vmcnt(16). nt stores count in vmcnt identically.
// ---------------------------------------------------------------------------
__global__ __launch_bounds__(256, 4) void attn_kern(
    const unsigned short* __restrict__ Qb, const unsigned short* __restrict__ Kb,
    const unsigned short* __restrict__ Vt, const unsigned long long* __restrict__ mbits,
    float* __restrict__ att, unsigned short* __restrict__ Obuf) {
  const int id0 = blockIdx.x + 32 * (blockIdx.y + 16 * blockIdx.z);
  const int id = (id0 & 7) * 128 + (id0 >> 3);
  const int qt = id & 31, h = (id >> 5) & 15, b = id >> 9;
  const int t = threadIdx.x, wave = t >> 6, lane = t & 63;
  const int q0 = qt * 64;
  const int c = lane & 15, gq = lane >> 4;
  const int srow = lane >> 3;                       // 0..7
  const int scol_sw = ((lane & 7) ^ srow) * 8;      // pre-swizzled source col
  const float SCALE = 0.125f * 1.44269504088896341f;  // (1/8)*log2(e)

  __shared__ alignas(16) unsigned short kt[2][64 * 64];   // 16 KB
  __shared__ alignas(16) unsigned short vt[2][64 * 64];   // 16 KB
  __shared__ alignas(16) unsigned short psfb[4][16 * 64]; // 8 KB bf16 P

  auto stage_k = [&](int kvt, int bu) {
#pragma unroll
    for (int i = 0; i < 2; ++i)
      gload_lds16(&Kb[(b * 2048 + kvt * 64 + wave * 16 + i * 8 + srow) * 1024 +
                      h * 64 + scol_sw],
                  &kt[bu][(wave * 16 + i * 8) * 64]);
  };
  auto stage_v = [&](int kvt, int bu) {
#pragma unroll
    for (int i = 0; i < 2; ++i)
      gload_lds16(&Vt[(b << 21) + (h * 64 + wave * 16 + i * 8 + srow) * 2048 +
                      kvt * 64 + scol_sw],
                  &vt[bu][(wave * 16 + i * 8) * 64]);
  };
  auto rdcol = [&](int ks) { return (((ks * 4 + gq) ^ (c & 7)) * 8); };

  stage_k(0, 0);

  // mask staging via vt region (dead until phase-2 prologue). Each wave
  // writes & reads only its own 16 rows -> wave-local in-order DS.
  unsigned long long* msk = (unsigned long long*)vt;  // [64][32]
  {
    const int row = t >> 2, c8 = (t & 3) * 8;
    const unsigned long long* src = &mbits[(unsigned)(b * 2048 + q0 + row) * 32 + c8];
#pragma unroll
    for (int j = 0; j < 8; ++j) msk[row * 32 + c8 + j] = src[j];
  }
  __builtin_amdgcn_sched_barrier(0);
  unsigned long long mlo[4], mhi[4];
#pragma unroll
  for (int r = 0; r < 4; ++r) {
    const int row = wave * 16 + gq * 4 + r;
    unsigned long long lo = 0, hi = 0;
#pragma unroll
    for (int kvi = 0; kvi < 16; ++kvi) {
      const unsigned long long w0 = msk[row * 32 + kvi] >> c;
      const unsigned long long w1 = msk[row * 32 + 16 + kvi] >> c;
      const unsigned long long n0 =
          (w0 & 1) | ((w0 >> 15) & 2) | ((w0 >> 30) & 4) | ((w0 >> 45) & 8);
      const unsigned long long n1 =
          (w1 & 1) | ((w1 >> 15) & 2) | ((w1 >> 30) & 4) | ((w1 >> 45) & 8);
      lo |= n0 << (kvi * 4);
      hi |= n1 << (kvi * 4);
    }
    mlo[r] = lo;
    mhi[r] = hi;
  }

  short8 aq[2];
  {
    const unsigned short* qrow = &Qb[(b * 2048 + q0 + wave * 16 + c) * 1024 + h * 64];
    aq[0] = *(const short8*)&qrow[gq * 8];
    aq[1] = *(const short8*)&qrow[32 + gq * 8];
  }

  asm volatile("s_waitcnt vmcnt(0) lgkmcnt(0)" ::: "memory");
  __builtin_amdgcn_s_barrier();
  __builtin_amdgcn_sched_barrier(0);

  const f32x4 zero = {0.f, 0.f, 0.f, 0.f};
  float lsum[4] = {0.f, 0.f, 0.f, 0.f};
  int buf = 0;

  // ---- phase 1: row sums of 2^e' ----
#pragma unroll 1
  for (int kv = 0; kv < 32; ++kv) {
    if (kv < 31) {
      stage_k(kv + 1, buf ^ 1);
      asm volatile("s_waitcnt vmcnt(2)" ::: "memory");
    } else {
      asm volatile("s_waitcnt vmcnt(0)" ::: "memory");
    }
    __builtin_amdgcn_s_barrier();
    __builtin_amdgcn_sched_barrier(0);

    f32x4 s[4];
#pragma unroll
    for (int nt = 0; nt < 4; ++nt) s[nt] = zero;
    __builtin_amdgcn_s_setprio(1);
#pragma unroll
    for (int ks = 0; ks < 2; ++ks)
#pragma unroll
      for (int nt = 0; nt < 4; ++nt) {
        const short8 bk = *(const short8*)&kt[buf][(nt * 16 + c) * 64 + rdcol(ks)];
        s[nt] = mfma_bf16(aq[ks], bk, s[nt]);
      }
    __builtin_amdgcn_s_setprio(0);
#pragma unroll
    for (int r = 0; r < 4; ++r) {
      const unsigned long long mr = (kv < 16) ? mlo[r] : mhi[r];
      const unsigned nib = (unsigned)(mr >> ((kv & 15) * 4)) & 0xFu;
#pragma unroll
      for (int nt = 0; nt < 4; ++nt) {
        const float e = ((nib >> nt) & 1u) ? s[nt][r] * SCALE : -30.f;
        lsum[r] += __builtin_amdgcn_exp2f(e);
      }
    }
    asm volatile("s_waitcnt lgkmcnt(0)" ::: "memory");
    __builtin_amdgcn_s_barrier();
    __builtin_amdgcn_sched_barrier(0);
    buf ^= 1;
  }

  float linv[4];
#pragma unroll
  for (int r = 0; r < 4; ++r) {
    float v = lsum[r];
    v += __shfl_xor(v, 1);
    v += __shfl_xor(v, 2);
    v += __shfl_xor(v, 4);
    v += __shfl_xor(v, 8);
    linv[r] = 1.0f / v;
  }

  f32x4 o[4];
#pragma unroll
  for (int nt = 0; nt < 4; ++nt) o[nt] = zero;

  // ---- phase 2 prologue: stage K0+V0 (buf == 0 after 32 toggles) ----
  stage_k(0, buf);
  stage_v(0, buf);
  asm volatile("s_waitcnt vmcnt(0)" ::: "memory");
  __builtin_amdgcn_s_barrier();
  __builtin_amdgcn_sched_barrier(0);

  // att row bases: row = q0+wave*16+gq*4+r, starting col = c; advance 64/iter.
  float* attb[4];
#pragma unroll
  for (int r = 0; r < 4; ++r)
    attb[r] = att + (long)((b * 16 + h) * 2048 + q0 + wave * 16 + gq * 4 + r) * 2048 + c;

  unsigned short* pw = &psfb[wave][0];

  // ---- phase 2: store fp32 attention from regs, accumulate O = P @ V ----
#pragma unroll 1
  for (int kv = 0; kv < 32; ++kv) {
    if (kv < 31) {
      stage_k(kv + 1, buf ^ 1);
      stage_v(kv + 1, buf ^ 1);
      // queue: [L_kv(4), S_{kv-1}(16), L_{kv+1}(4)] -> vmcnt(20) retires L_kv.
      asm volatile("s_waitcnt vmcnt(20)" ::: "memory");
    } else {
      // queue: [L_31(4), S_30(16)] -> vmcnt(16) retires L_31.
      asm volatile("s_waitcnt vmcnt(16)" ::: "memory");
    }
    __builtin_amdgcn_s_barrier();
    __builtin_amdgcn_sched_barrier(0);

    f32x4 s[4];
#pragma unroll
    for (int nt = 0; nt < 4; ++nt) s[nt] = zero;
    __builtin_amdgcn_s_setprio(1);
#pragma unroll
    for (int ks = 0; ks < 2; ++ks)
#pragma unroll
      for (int nt = 0; nt < 4; ++nt) {
        const short8 bk = *(const short8*)&kt[buf][(nt * 16 + c) * 64 + rdcol(ks)];
        s[nt] = mfma_bf16(aq[ks], bk, s[nt]);
      }
    __builtin_amdgcn_s_setprio(0);

    // p = exp2(e)*linv: nt-store att directly (no L2 allocate), and write
    // bf16 P to psfb (XOR-swizzled) for the PV A-operand.
#pragma unroll
    for (int r = 0; r < 4; ++r) {
      const unsigned long long mr = (kv < 16) ? mlo[r] : mhi[r];
      const unsigned nib = (unsigned)(mr >> ((kv & 15) * 4)) & 0xFu;
      const int prow = gq * 4 + r;
      const int sw = (prow & 7) << 3;
#pragma unroll
      for (int nt = 0; nt < 4; ++nt) {
        const float e = ((nib >> nt) & 1u) ? s[nt][r] * SCALE : -30.f;
        const float p = __builtin_amdgcn_exp2f(e) * linv[r];
        __builtin_nontemporal_store(p, attb[r] + nt * 16);   // global dword, nt
        pw[prow * 64 + ((nt * 16 + c) ^ sw)] = f2bf(p);      // ds_write_b16
      }
      attb[r] += 64;
    }
    __builtin_amdgcn_sched_barrier(0);  // pin psfb writes before A-read

    // PV accumulate: A-frag direct from psfb (bf16, swizzled), wave-local.
#pragma unroll
    for (int ks = 0; ks < 2; ++ks) {
      const short8 ap =
          *(const short8*)&pw[c * 64 + ((ks * 32 + gq * 8) ^ ((c & 7) << 3))];
      __builtin_amdgcn_s_setprio(1);
#pragma unroll
      for (int nt = 0; nt < 4; ++nt) {
        const short8 bv = *(const short8*)&vt[buf][(nt * 16 + c) * 64 + rdcol(ks)];
        o[nt] = mfma_bf16(ap, bv, o[nt]);
      }
      __builtin_amdgcn_s_setprio(0);
    }
    asm volatile("s_waitcnt lgkmcnt(0)" ::: "memory");  // kt/vt/psfb reads done
    __builtin_amdgcn_s_barrier();
    __builtin_amdgcn_sched_barrier(0);
    buf ^= 1;
  }

  // store O (bf16) in [B,S,H*DV] (re-read by final GEMM -> keep cacheable)
#pragma unroll
  for (int nt = 0; nt < 4; ++nt)
#pragma unroll
    for (int r = 0; r < 4; ++r) {
      const int row = q0 + wave * 16 + gq * 4 + r;
      Obuf[(b * 2048 + row) * 1024 + h * 64 + nt * 16 + c] = f2bf(o[nt][r]);
    }
}

// ---------------------------------------------------------------------------
extern "C" void kernel_launch(void* const* d_in, const int* in_sizes, int n_in,
                              void* d_out, int out_size, void* d_ws, size_t ws_size,
                              hipStream_t stream) {
  const float* query = (const float*)d_in[0];
  const float* key   = (const float*)d_in[1];
  const float* value = (const float*)d_in[2];
  const int* mask    = (const int*)d_in[3];
  const float* Wq = (const float*)d_in[4];
  const float* bq = (const float*)d_in[5];
  const float* Wk = (const float*)d_in[6];
  const float* bk = (const float*)d_in[7];
  const float* Wv = (const float*)d_in[8];
  const float* bv = (const float*)d_in[9];
  const float* Wo = (const float*)d_in[10];
  const float* bo = (const float*)d_in[11];

  float* out = (float*)d_out;
  float* att = out + 4194304;  // B*S*D fp32, then B*H*S*S fp32

  char* ws = (char*)d_ws;
  const size_t MB = 1u << 20;
  unsigned short* Aq   = (unsigned short*)(ws);            // bf16 query
  unsigned short* Ak   = (unsigned short*)(ws + 8 * MB);   // bf16 key
  unsigned short* Av   = (unsigned short*)(ws + 16 * MB);  // bf16 value
  unsigned short* Qb   = (unsigned short*)(ws + 24 * MB);
  unsigned short* Kb   = (unsigned short*)(ws + 32 * MB);
  unsigned short* Vt   = (unsigned short*)(ws + 40 * MB);
  unsigned short* Obuf = (unsigned short*)(ws + 48 * MB);
  unsigned short* WqT  = (unsigned short*)(ws + 56 * MB);
  unsigned short* WkT  = (unsigned short*)(ws + 58 * MB);
  unsigned short* WvT  = (unsigned short*)(ws + 60 * MB);
  unsigned short* WoT  = (unsigned short*)(ws + 62 * MB);
  unsigned long long* mbits = (unsigned long long*)(ws + 64 * MB);

  conv_f32_bf16<<<dim3(2048, 1, 3), 256, 0, stream>>>(query, key, value, Aq, Ak, Av);
  transpose_w<<<dim3(16, 16, 4), 256, 0, stream>>>(Wq, Wk, Wv, Wo, WqT, WkT, WvT, WoT);
  mask_prep<<<dim3(512), 256, 0, stream>>>(mask, mbits);

  GArg gq{Aq, WqT, bq, Qb, 0};
  GArg gk{Ak, WkT, bk, Kb, 0};
  GArg gv{Av, WvT, bv, Vt, 1};
  gemm_bt<<<dim3(8, 32, 3), 256, 0, stream>>>(gq, gk, gv);

  attn_kern<<<dim3(32, 16, 2), 256, 0, stream>>>(Qb, Kb, Vt, mbits, att, Obuf);

  GArg go{Obuf, WoT, bo, out, 2};
  gemm_bt<<<dim3(8, 32, 1), 256, 0, stream>>>(go, go, go);
}